// Round 1
// baseline (60.896 us; speedup 1.0000x reference)
//
#include <hip/hip_runtime.h>

// RoPE, fp32, d_k=128, theta=10000.
// out[..,2k]   = cos(a)*x[..,2k] - sin(a)*x[..,2k+1]
// out[..,2k+1] = sin(a)*x[..,2k] + cos(a)*x[..,2k+1],  a = pos[s]*theta^(-k/64)
//
// v2: batch-reuse. Angles depend only on (s,k), not batch. One thread owns
// one float4 position of ONE batch slice (i in [0, seq*32)), computes
// sin/cos once, applies to all nbatch slices. This removes the runtime
// `% seq` division (s = i>>5, d4 = i&31) and cuts transcendental work 4x.
// Memory: 4 independent coalesced float4 streams per thread; in-flight
// bytes per CU unchanged vs v1 (8 waves/CU x 4 loads x 1KB = 32KB).
//
// Trig via hardware v_sin_f32/v_cos_f32 in the REVOLUTIONS domain:
//   rev = (pos/2pi) * theta^(-k/64);  r = fract(rev);  sin(2*pi*r)
// Explicit fract required: |rev| can reach ~651, outside HW valid range.
// Precision verified previously: ~1e-3 rad angle error vs 0.114 threshold.

#define D_K 128

__global__ __launch_bounds__(256) void rope_kernel(
    const float4* __restrict__ x4,
    const int*    __restrict__ pos,
    float4*       __restrict__ out4,
    int nrow4,      // float4s per batch slice = seq * D_K/4
    int nbatch)     // batch count
{
    int i = blockIdx.x * blockDim.x + threadIdx.x;
    if (i >= nrow4) return;

    int d4 = i & (D_K / 4 - 1);   // float4 index within head dim: 0..31
    int s  = i >> 5;              // token index (D_K/4 == 32)

    // p_rev = pos / (2*pi)
    float p_rev = (float)pos[s] * 0.15915494309189535f;

    // inv_freq(k) = theta^(-k/64) = exp2(-k * log2(theta)/64)
    const float L    = 0.20762050593046014f;   // log2(10000)/64
    const float STEP = 0.86596432336006535f;   // theta^(-1/64) = exp2(-L)
    int   k0 = d4 << 1;                        // pair index of .x/.y
    float f0 = __builtin_amdgcn_exp2f(-L * (float)k0);
    float f1 = f0 * STEP;

    float r0 = __builtin_amdgcn_fractf(p_rev * f0);
    float r1 = __builtin_amdgcn_fractf(p_rev * f1);

    float s0 = __builtin_amdgcn_sinf(r0);   // sin(2*pi*r0)
    float c0 = __builtin_amdgcn_cosf(r0);
    float s1 = __builtin_amdgcn_sinf(r1);
    float c1 = __builtin_amdgcn_cosf(r1);

    #pragma unroll 4
    for (int b = 0; b < nbatch; ++b) {
        int idx = i + b * nrow4;
        float4 v = x4[idx];
        float4 o;
        o.x = c0 * v.x - s0 * v.y;
        o.y = s0 * v.x + c0 * v.y;
        o.z = c1 * v.z - s1 * v.w;
        o.w = s1 * v.z + c1 * v.w;
        out4[idx] = o;
    }
}

extern "C" void kernel_launch(void* const* d_in, const int* in_sizes, int n_in,
                              void* d_out, int out_size, void* d_ws, size_t ws_size,
                              hipStream_t stream) {
    const float4* x4  = (const float4*)d_in[0];
    const int*    pos = (const int*)d_in[1];
    float4*       o4  = (float4*)d_out;

    int n     = in_sizes[0];            // total fp32 elements of x (4*4096*128)
    int seq   = in_sizes[1];            // 4096
    int n4    = n / 4;                  // total float4s
    int nrow4 = seq * (D_K / 4);        // float4s in one batch slice
    int nbatch = n4 / nrow4;            // 4

    int block = 256;
    int grid  = (nrow4 + block - 1) / block;   // 512 blocks
    rope_kernel<<<grid, block, 0, stream>>>(x4, pos, o4, nrow4, nbatch);
}